// Round 11
// baseline (450.164 us; speedup 1.0000x reference)
//
#include <hip/hip_runtime.h>

// 4D conv net, MI355X. S=30, B=2, ch 1->10->10->1, kernel 3^4, pad 1, ReLU.
// out = net(x,w) + net(x,w_swap), w_swap has (k1,k2)<->(k3,k4).
// R7: all layers as 32x32x16 bf16 MFMA, M = 32 padded t-positions, K = 16
// channels, N = k4*10+co. Cross-k4 combine in epilogue via per-wave LDS.
// R8: XCD-chunk swizzle, full-line stores, barrier-free epilogue.
// R12: uniform straight-line tap body (junk rows). R13: layer-0 K-packed
// conv0_k. R17: B-table in LDS (ds_read_b128), 72 -> 69 us.
// R18: occupancy ladder analysis: effective per-SIMD reg pool ~384;
// total regs (arch+64 AGPR) <= 128 <=> 3 waves/SIMD (R8: 124 -> 37% occ),
// > 128 <=> 2 (R10/R17: 136-144 -> 27%). R12==R13 proved the A/B double
// state buys nothing, but its ~30 regs cost the third wave. R18 drops all
// prefetch state: per-tap 6 A-loads (immediate offsets, single conditional
// off5 for the wv3/half1 clamp) + 3 B ds_reads; launch_bounds(256,4).
// Verify: VGPR ~56-64, occupancy ~37%, dur 69 -> ~50-57.

static constexpr int S  = 30;
static constexpr long S4 = 810000;
static constexpr size_t PLANE = 32768;                  // 32*32*16*2 B
static constexpr size_t YBYTES = (size_t)1800 * PLANE;  // [b(2)][g1][g2]

typedef __bf16 bf16x8 __attribute__((ext_vector_type(8)));
typedef float  f32x16 __attribute__((ext_vector_type(16)));
typedef unsigned int  u32;
typedef unsigned short u16;

static __device__ __forceinline__ u16 f2bf(float f) {
    u32 u = __builtin_bit_cast(u32, f);
    return (u16)((u + 0x7fffu + ((u >> 16) & 1u)) >> 16);
}

// ---------------------------------------------------------------------------
// B-fragment tables.
// Main: [set(6)][k12(9)][k3(3)][lane(64)] uint4 (sets 0/1 unused).
// L0-packed (appended): [branch(2)][k3(3)][lane(64)] uint4,
//   B[k=k12][n=k4*10+co] = w1[co, perm(k1,k2,k3,k4)], k12 = hl*8+j (<9).
__global__ __launch_bounds__(256) void fragprep_k(u32* __restrict__ ft,
    const float* __restrict__ w1, const float* __restrict__ w2,
    const float* __restrict__ w3)
{
    const int gid = blockIdx.x * 256 + threadIdx.x;
    if (gid >= 6 * 27 * 64 + 2 * 3 * 64) return;
    const int lane = gid & 63;
    const int n = lane & 31, hl = lane >> 5;
    u16 us[8];
#pragma unroll
    for (int j = 0; j < 8; ++j) us[j] = 0;

    if (gid < 6 * 27 * 64) {
        int r = gid >> 6;
        const int k3 = r % 3; r /= 3;
        const int k12 = r % 9; const int set = r / 9;
        const int layer = set >> 1, swap = set & 1;
        const int k1 = k12 / 3, k2 = k12 % 3;
        if (n < 30) {
            const int k4 = (n < 10) ? 0 : ((n < 20) ? 1 : 2);
            const int co = n - 10 * k4;
            const int i1 = swap ? k3 : k1, i2 = swap ? k4 : k2;
            const int i3 = swap ? k1 : k3, i4 = swap ? k2 : k4;
            const int widx = ((i1 * 3 + i2) * 3 + i3) * 3 + i4;
#pragma unroll
            for (int j = 0; j < 8; ++j) {
                const int k = hl * 8 + j;
                float wv = 0.f;
                if (layer == 0) { if (k == 0) wv = w1[co * 81 + widx]; }
                else if (layer == 1) { if (k < 10) wv = w2[(co * 10 + k) * 81 + widx]; }
                else { if (k < 10 && co == 0) wv = w3[k * 81 + widx]; }
                us[j] = f2bf(wv);
            }
        }
    } else {
        const int idx = gid - 6 * 27 * 64;       // 0..383
        int r = idx >> 6;                        // 0..5
        const int k3 = r % 3, swap = r / 3;
        if (n < 30) {
            const int k4 = (n < 10) ? 0 : ((n < 20) ? 1 : 2);
            const int co = n - 10 * k4;
#pragma unroll
            for (int j = 0; j < 8; ++j) {
                const int k12 = hl * 8 + j;
                if (k12 < 9) {
                    const int k1 = k12 / 3, k2 = k12 % 3;
                    const int i1 = swap ? k3 : k1, i2 = swap ? k4 : k2;
                    const int i3 = swap ? k1 : k3, i4 = swap ? k2 : k4;
                    const int widx = ((i1 * 3 + i2) * 3 + i3) * 3 + i4;
                    us[j] = f2bf(w1[co * 81 + widx]);
                }
            }
        }
    }
    u32* o = ft + (size_t)gid * 4;
    o[0] = (u32)us[0] | ((u32)us[1] << 16);
    o[1] = (u32)us[2] | ((u32)us[3] << 16);
    o[2] = (u32)us[4] | ((u32)us[5] << 16);
    o[3] = (u32)us[6] | ((u32)us[7] << 16);
}

// ---------------------------------------------------------------------------
// Zero halo positions (h' or t' in {0,31}) of all 1800 planes of y1 and y2.
__global__ __launch_bounds__(128) void zerok(u16* __restrict__ y1, u16* __restrict__ y2)
{
    const int pb = blockIdx.x, tid = threadIdx.x;
    if (tid >= 124) return;
    int hp, tp;
    if (tid < 32)      { hp = 0;        tp = tid; }
    else if (tid < 64) { hp = 31;       tp = tid - 32; }
    else if (tid < 94) { hp = tid - 63; tp = 0; }
    else               { hp = tid - 93; tp = 31; }
    const size_t off = (size_t)pb * PLANE + hp * 1024 + tp * 32;
    const uint4 z = make_uint4(0, 0, 0, 0);
    *(uint4*)((char*)y1 + off)      = z;
    *(uint4*)((char*)y1 + off + 16) = z;
    *(uint4*)((char*)y2 + off)      = z;
    *(uint4*)((char*)y2 + off + 16) = z;
}

// ---------------------------------------------------------------------------
// Layer 0, K-packed: one "tap", 12 MFMAs per wave (unchanged from R13).
__global__ __launch_bounds__(256, 4) void conv0_k(
    const float* __restrict__ x, const uint4* __restrict__ bt,
    const float* __restrict__ bias, void* __restrict__ outp)
{
    __shared__ float E[4][1056];
    const int wgid = blockIdx.x + S * blockIdx.y + 900 * blockIdx.z;
    const int id2  = (wgid & 7) * 450 + (wgid >> 3);
    const int half = id2 & 1;
    int sp = id2 >> 1;
    const int w1i = sp % S; sp /= S;
    const int h1  = sp % S;
    const int b   = sp / S;

    const int tid = threadIdx.x;
    const int lane = tid & 63, wv = tid >> 6;
    const int m = lane & 31, hl = lane >> 5;
    const int rbase = half * 15 + wv * 4;

    uint4 Bs[3];
#pragma unroll
    for (int ss = 0; ss < 3; ++ss) Bs[ss] = bt[ss * 64 + lane];

    int gof[9]; int gokm = 0;
#pragma unroll
    for (int k12 = 0; k12 < 9; ++k12) {
        const int g1 = h1 + k12 / 3 - 1, g2 = w1i + k12 % 3 - 1;
        gof[k12] = 0;
        if (g1 >= 0 && g1 < S && g2 >= 0 && g2 < S) {
            gof[k12] = (g1 * S + g2) * 900; gokm |= 1 << k12;
        }
    }
    const float* xb = x + (size_t)b * S4;

    uint4 F[6];
#pragma unroll
    for (int f = 0; f < 6; ++f) {
        const int hp = rbase + f;
        const bool rk = (hp >= 1 && hp <= 30 && m >= 1 && m <= 30);
        const int ro = (hp - 1) * 30 + (m - 1);
        u16 av[8];
#pragma unroll
        for (int j = 0; j < 8; ++j) av[j] = 0;
        if (hl == 0) {
#pragma unroll
            for (int j = 0; j < 8; ++j) {
                float v = 0.f;
                if (rk && ((gokm >> j) & 1)) v = xb[gof[j] + ro];
                av[j] = f2bf(v);
            }
        } else {
            float v = 0.f;
            if (rk && ((gokm >> 8) & 1)) v = xb[gof[8] + ro];
            av[0] = f2bf(v);
        }
        F[f] = make_uint4((u32)av[0] | ((u32)av[1] << 16),
                          (u32)av[2] | ((u32)av[3] << 16),
                          (u32)av[4] | ((u32)av[5] << 16),
                          (u32)av[6] | ((u32)av[7] << 16));
    }

    f32x16 acc[4];
#pragma unroll
    for (int r = 0; r < 4; ++r)
#pragma unroll
        for (int e = 0; e < 16; ++e) acc[r][e] = 0.f;
#pragma unroll
    for (int ss = 0; ss < 3; ++ss)
#pragma unroll
        for (int r = 0; r < 4; ++r)
            acc[r] = __builtin_amdgcn_mfma_f32_32x32x16_bf16(
                __builtin_bit_cast(bf16x8, F[r + ss]),
                __builtin_bit_cast(bf16x8, Bs[ss]), acc[r], 0, 0, 0);

    float* Ew = E[wv];
    for (int r = 0; r < 4; ++r) {
        if (wv == 3 && r == 3) continue;
#pragma unroll
        for (int gq = 0; gq < 4; ++gq)
#pragma unroll
            for (int r4 = 0; r4 < 4; ++r4)
                Ew[m * 33 + 4 * hl + 8 * gq + r4] = acc[r][gq * 4 + r4];

        const int h2 = rbase + r;
        char* pl = (char*)outp + ((size_t)b * 900 + h1 * S + w1i) * PLANE
                   + (size_t)(h2 + 1) * 1024;
        const int t = lane >> 1, h8 = lane & 1;
        if (t < 30) {
            u32 wo[4];
#pragma unroll
            for (int p = 0; p < 4; ++p) {
                const int c0 = 8 * h8 + 2 * p, c1 = c0 + 1;
                float v0 = 0.f, v1 = 0.f;
                if (c0 < 10)
                    v0 = fmaxf(Ew[c0 * 33 + t] + Ew[(10 + c0) * 33 + t + 1]
                             + Ew[(20 + c0) * 33 + t + 2] + bias[c0], 0.f);
                if (c1 < 10)
                    v1 = fmaxf(Ew[c1 * 33 + t] + Ew[(10 + c1) * 33 + t + 1]
                             + Ew[(20 + c1) * 33 + t + 2] + bias[c1], 0.f);
                wo[p] = (u32)f2bf(v0) | ((u32)f2bf(v1) << 16);
            }
            *(uint4*)(pl + (t + 1) * 32 + h8 * 16) =
                make_uint4(wo[0], wo[1], wo[2], wo[3]);
        }
    }
}

// ---------------------------------------------------------------------------
// Layers 1/2: LEAN tap loop — no prefetch state. Per tap: 6 A-loads
// (immediate offsets off the row base; off5 conditionally clamps the one
// wv3/half1 OOB row) + 3 B ds_reads from the staged LDS table + 12 MFMAs.
// Register budget: F 24 + B 12 + addr ~20 + 64 AGPR <= 128 total ->
// 3 waves/SIMD. LDS 44.5 KB -> 3 blocks/CU.
template<int LAYER, bool ACCUM>
__global__ __launch_bounds__(256, 4) void conv_k(
    const void* __restrict__ inp, const u32* __restrict__ ftab,
    const float* __restrict__ bias, void* __restrict__ outp)
{
    __shared__ float E[4][1056];          // per-wave epilogue scratch
    __shared__ uint4 BT[1728];            // [k12(9)][k3(3)][lane(64)]

    const int tid = threadIdx.x;
    // ---- stage B table to LDS (27.6 KB, once per block) ----
    {
        const uint4* g = (const uint4*)ftab;
#pragma unroll
        for (int j = 0; j < 7; ++j) {
            const int idx = j * 256 + tid;
            if (idx < 1728) BT[idx] = g[idx];
        }
    }
    __syncthreads();

    const int wgid = blockIdx.x + S * blockIdx.y + 900 * blockIdx.z;
    const int id2  = (wgid & 7) * 450 + (wgid >> 3);
    const int half = id2 & 1;
    int sp = id2 >> 1;
    const int w1i = sp % S; sp /= S;
    const int h1  = sp % S;
    const int b   = sp / S;

    const int lane = tid & 63, wv = tid >> 6;
    const int m = lane & 31, hl = lane >> 5;
    const int rbase = half * 15 + wv * 4;
    // Only rbase==27 (wv3, half1) would read row 32: clamp its f=5 to row 31
    // (feeds only the junk acc[3], never stored).
    const int off5 = (rbase == 27) ? 4096 : 5120;

    int kl[9], nk = 0;
#pragma unroll
    for (int k12 = 0; k12 < 9; ++k12) {
        const int g1 = h1 + k12 / 3 - 1, g2 = w1i + k12 % 3 - 1;
        if (g1 >= 0 && g1 < S && g2 >= 0 && g2 < S)
            kl[nk++] = (g1 * S + g2) | (k12 << 10);
    }

    f32x16 acc[4];
#pragma unroll
    for (int r = 0; r < 4; ++r)
#pragma unroll
        for (int e = 0; e < 16; ++e) acc[r][e] = 0.f;

    const char* Pb = (const char*)inp + (size_t)b * 900 * PLANE
                     + (size_t)rbase * 1024 + m * 32 + hl * 16;

    for (int ki = 0; ki < nk; ++ki) {
        const int g = kl[ki] & 1023, kk = kl[ki] >> 10;
        const char* P = Pb + (size_t)g * PLANE;
        uint4 F[6];
        F[0] = *(const uint4*)(P);
        F[1] = *(const uint4*)(P + 1024);
        F[2] = *(const uint4*)(P + 2048);
        F[3] = *(const uint4*)(P + 3072);
        F[4] = *(const uint4*)(P + 4096);
        F[5] = *(const uint4*)(P + off5);
        uint4 B0[3];
#pragma unroll
        for (int f = 0; f < 3; ++f) B0[f] = BT[(kk * 3 + f) * 64 + lane];

        // s-outer / r-inner: 4 independent MFMAs between dependent pairs
#pragma unroll
        for (int ss = 0; ss < 3; ++ss)
#pragma unroll
            for (int r = 0; r < 4; ++r)
                acc[r] = __builtin_amdgcn_mfma_f32_32x32x16_bf16(
                    __builtin_bit_cast(bf16x8, F[r + ss]),
                    __builtin_bit_cast(bf16x8, B0[ss]), acc[r], 0, 0, 0);
    }

    // ---- epilogue: per-wave LDS transpose, combine k4 shifts (barrier-free)
    float* Ew = E[wv];
    for (int r = 0; r < 4; ++r) {
        if (wv == 3 && r == 3) continue;
#pragma unroll
        for (int gq = 0; gq < 4; ++gq)
#pragma unroll
            for (int r4 = 0; r4 < 4; ++r4)
                Ew[m * 33 + 4 * hl + 8 * gq + r4] = acc[r][gq * 4 + r4];

        const int h2 = rbase + r;
        if (LAYER <= 1) {
            char* pl = (char*)outp + ((size_t)b * 900 + h1 * S + w1i) * PLANE
                       + (size_t)(h2 + 1) * 1024;
            const int t = lane >> 1, h8 = lane & 1;
            if (t < 30) {
                u32 wo[4];
#pragma unroll
                for (int p = 0; p < 4; ++p) {
                    const int c0 = 8 * h8 + 2 * p, c1 = c0 + 1;
                    float v0 = 0.f, v1 = 0.f;
                    if (c0 < 10)
                        v0 = fmaxf(Ew[c0 * 33 + t] + Ew[(10 + c0) * 33 + t + 1]
                                 + Ew[(20 + c0) * 33 + t + 2] + bias[c0], 0.f);
                    if (c1 < 10)
                        v1 = fmaxf(Ew[c1 * 33 + t] + Ew[(10 + c1) * 33 + t + 1]
                                 + Ew[(20 + c1) * 33 + t + 2] + bias[c1], 0.f);
                    wo[p] = (u32)f2bf(v0) | ((u32)f2bf(v1) << 16);
                }
                *(uint4*)(pl + (t + 1) * 32 + h8 * 16) =
                    make_uint4(wo[0], wo[1], wo[2], wo[3]);
            }
        } else {
            if (lane < 30) {
                const int t = lane;
                float v = Ew[t] + Ew[330 + t + 1] + Ew[660 + t + 2] + bias[0];
                v = fmaxf(v, 0.f);
                float* o = (float*)outp + (size_t)b * S4
                           + (size_t)(h1 * S + w1i) * 900 + h2 * 30 + t;
                if (ACCUM) *o += v; else *o = v;
            }
        }
    }
}

// ---------------------------------------------------------------------------
extern "C" void kernel_launch(void* const* d_in, const int* in_sizes, int n_in,
                              void* d_out, int out_size, void* d_ws, size_t ws_size,
                              hipStream_t stream)
{
    const float* x   = (const float*)d_in[0];
    const float* w1p = (const float*)d_in[1];
    const float* b1p = (const float*)d_in[2];
    const float* w2p = (const float*)d_in[3];
    const float* b2p = (const float*)d_in[4];
    const float* w3p = (const float*)d_in[5];
    const float* b3p = (const float*)d_in[6];
    float* out = (float*)d_out;

    // ws: fragtab (6*27*64 + 2*3*64) uint4 = 172032 B | y1 59 MB | y2 59 MB
    u32* ft = (u32*)d_ws;
    const uint4* ftL0 = (const uint4*)d_ws + 6 * 27 * 64;
    u16* y1 = (u16*)((char*)d_ws + 172032);
    u16* y2 = (u16*)((char*)y1 + YBYTES);

    fragprep_k<<<42, 256, 0, stream>>>(ft, w1p, w2p, w3p);
    zerok<<<1800, 128, 0, stream>>>(y1, y2);

    dim3 grid(S, S, 4), blk(256);
    for (int br = 0; br < 2; ++br) {
        const u32* f2 = ft + (size_t)(2 + br) * 27 * 64 * 4;
        const u32* f3 = ft + (size_t)(4 + br) * 27 * 64 * 4;
        conv0_k<<<grid, blk, 0, stream>>>(x, ftL0 + br * 192, b1p, (void*)y1);
        conv_k<1, false><<<grid, blk, 0, stream>>>(y1, f2, b2p, (void*)y2);
        if (br == 0)
            conv_k<2, false><<<grid, blk, 0, stream>>>(y2, f3, b3p, (void*)out);
        else
            conv_k<2, true><<<grid, blk, 0, stream>>>(y2, f3, b3p, (void*)out);
    }
}

// Round 12
// 418.478 us; speedup vs baseline: 1.0757x; 1.0757x over previous
//
#include <hip/hip_runtime.h>

// 4D conv net, MI355X. S=30, B=2, ch 1->10->10->1, kernel 3^4, pad 1, ReLU.
// out = net(x,w) + net(x,w_swap), w_swap has (k1,k2)<->(k3,k4).
// R7: all layers as 32x32x16 bf16 MFMA, M = 32 padded t-positions, K = 16
// channels, N = k4*10+co. Cross-k4 combine in epilogue via per-wave LDS.
// R8: XCD-chunk swizzle, full-line stores. R13: layer-0 K-packed conv0_k.
// R17 (best, 69 us/dispatch): B-table in LDS, rotate-A depth-1 prefetch.
// R18: forced (256,4) on a 136-reg body -> allocator spilled (LDS 44544->
// 53760) and lean loop lost the rotate pipeline -> 97 us. Register ladder
// confirmed: total(arch+AGPR) <= 128 <=> 37% occ (R8), >= 132 <=> ~26%.
// R19: make the budget close structurally: conv_k = 5 waves x 3 rows
// (320 thr). 15 rows = 5x3 exactly: no junk row (-1/16 MFMA work), no
// clamp; acc = 48 AGPR; rotate-A kept, B single ds_read -> arch ~75,
// total ~123 <= 128 -> 4 waves/SIMD, no spill under (320,4). Union E/BT
// LDS (E live only after taps; one barrier) -> 27648 B.

static constexpr int S  = 30;
static constexpr long S4 = 810000;
static constexpr size_t PLANE = 32768;                  // 32*32*16*2 B
static constexpr size_t YBYTES = (size_t)1800 * PLANE;  // [b(2)][g1][g2]

typedef __bf16 bf16x8 __attribute__((ext_vector_type(8)));
typedef float  f32x16 __attribute__((ext_vector_type(16)));
typedef unsigned int  u32;
typedef unsigned short u16;

static __device__ __forceinline__ u16 f2bf(float f) {
    u32 u = __builtin_bit_cast(u32, f);
    return (u16)((u + 0x7fffu + ((u >> 16) & 1u)) >> 16);
}

// ---------------------------------------------------------------------------
// B-fragment tables.
// Main: [set(6)][k12(9)][k3(3)][lane(64)] uint4 (sets 0/1 unused).
// L0-packed (appended): [branch(2)][k3(3)][lane(64)] uint4,
//   B[k=k12][n=k4*10+co] = w1[co, perm(k1,k2,k3,k4)], k12 = hl*8+j (<9).
__global__ __launch_bounds__(256) void fragprep_k(u32* __restrict__ ft,
    const float* __restrict__ w1, const float* __restrict__ w2,
    const float* __restrict__ w3)
{
    const int gid = blockIdx.x * 256 + threadIdx.x;
    if (gid >= 6 * 27 * 64 + 2 * 3 * 64) return;
    const int lane = gid & 63;
    const int n = lane & 31, hl = lane >> 5;
    u16 us[8];
#pragma unroll
    for (int j = 0; j < 8; ++j) us[j] = 0;

    if (gid < 6 * 27 * 64) {
        int r = gid >> 6;
        const int k3 = r % 3; r /= 3;
        const int k12 = r % 9; const int set = r / 9;
        const int layer = set >> 1, swap = set & 1;
        const int k1 = k12 / 3, k2 = k12 % 3;
        if (n < 30) {
            const int k4 = (n < 10) ? 0 : ((n < 20) ? 1 : 2);
            const int co = n - 10 * k4;
            const int i1 = swap ? k3 : k1, i2 = swap ? k4 : k2;
            const int i3 = swap ? k1 : k3, i4 = swap ? k2 : k4;
            const int widx = ((i1 * 3 + i2) * 3 + i3) * 3 + i4;
#pragma unroll
            for (int j = 0; j < 8; ++j) {
                const int k = hl * 8 + j;
                float wv = 0.f;
                if (layer == 0) { if (k == 0) wv = w1[co * 81 + widx]; }
                else if (layer == 1) { if (k < 10) wv = w2[(co * 10 + k) * 81 + widx]; }
                else { if (k < 10 && co == 0) wv = w3[k * 81 + widx]; }
                us[j] = f2bf(wv);
            }
        }
    } else {
        const int idx = gid - 6 * 27 * 64;       // 0..383
        int r = idx >> 6;                        // 0..5
        const int k3 = r % 3, swap = r / 3;
        if (n < 30) {
            const int k4 = (n < 10) ? 0 : ((n < 20) ? 1 : 2);
            const int co = n - 10 * k4;
#pragma unroll
            for (int j = 0; j < 8; ++j) {
                const int k12 = hl * 8 + j;
                if (k12 < 9) {
                    const int k1 = k12 / 3, k2 = k12 % 3;
                    const int i1 = swap ? k3 : k1, i2 = swap ? k4 : k2;
                    const int i3 = swap ? k1 : k3, i4 = swap ? k2 : k4;
                    const int widx = ((i1 * 3 + i2) * 3 + i3) * 3 + i4;
                    us[j] = f2bf(w1[co * 81 + widx]);
                }
            }
        }
    }
    u32* o = ft + (size_t)gid * 4;
    o[0] = (u32)us[0] | ((u32)us[1] << 16);
    o[1] = (u32)us[2] | ((u32)us[3] << 16);
    o[2] = (u32)us[4] | ((u32)us[5] << 16);
    o[3] = (u32)us[6] | ((u32)us[7] << 16);
}

// ---------------------------------------------------------------------------
// Zero halo positions (h' or t' in {0,31}) of all 1800 planes of y1 and y2.
__global__ __launch_bounds__(128) void zerok(u16* __restrict__ y1, u16* __restrict__ y2)
{
    const int pb = blockIdx.x, tid = threadIdx.x;
    if (tid >= 124) return;
    int hp, tp;
    if (tid < 32)      { hp = 0;        tp = tid; }
    else if (tid < 64) { hp = 31;       tp = tid - 32; }
    else if (tid < 94) { hp = tid - 63; tp = 0; }
    else               { hp = tid - 93; tp = 31; }
    const size_t off = (size_t)pb * PLANE + hp * 1024 + tp * 32;
    const uint4 z = make_uint4(0, 0, 0, 0);
    *(uint4*)((char*)y1 + off)      = z;
    *(uint4*)((char*)y1 + off + 16) = z;
    *(uint4*)((char*)y2 + off)      = z;
    *(uint4*)((char*)y2 + off + 16) = z;
}

// ---------------------------------------------------------------------------
// Layer 0, K-packed: one "tap", 12 MFMAs per wave (unchanged from R13).
__global__ __launch_bounds__(256, 4) void conv0_k(
    const float* __restrict__ x, const uint4* __restrict__ bt,
    const float* __restrict__ bias, void* __restrict__ outp)
{
    __shared__ float E[4][1056];
    const int wgid = blockIdx.x + S * blockIdx.y + 900 * blockIdx.z;
    const int id2  = (wgid & 7) * 450 + (wgid >> 3);
    const int half = id2 & 1;
    int sp = id2 >> 1;
    const int w1i = sp % S; sp /= S;
    const int h1  = sp % S;
    const int b   = sp / S;

    const int tid = threadIdx.x;
    const int lane = tid & 63, wv = tid >> 6;
    const int m = lane & 31, hl = lane >> 5;
    const int rbase = half * 15 + wv * 4;

    uint4 Bs[3];
#pragma unroll
    for (int ss = 0; ss < 3; ++ss) Bs[ss] = bt[ss * 64 + lane];

    int gof[9]; int gokm = 0;
#pragma unroll
    for (int k12 = 0; k12 < 9; ++k12) {
        const int g1 = h1 + k12 / 3 - 1, g2 = w1i + k12 % 3 - 1;
        gof[k12] = 0;
        if (g1 >= 0 && g1 < S && g2 >= 0 && g2 < S) {
            gof[k12] = (g1 * S + g2) * 900; gokm |= 1 << k12;
        }
    }
    const float* xb = x + (size_t)b * S4;

    uint4 F[6];
#pragma unroll
    for (int f = 0; f < 6; ++f) {
        const int hp = rbase + f;
        const bool rk = (hp >= 1 && hp <= 30 && m >= 1 && m <= 30);
        const int ro = (hp - 1) * 30 + (m - 1);
        u16 av[8];
#pragma unroll
        for (int j = 0; j < 8; ++j) av[j] = 0;
        if (hl == 0) {
#pragma unroll
            for (int j = 0; j < 8; ++j) {
                float v = 0.f;
                if (rk && ((gokm >> j) & 1)) v = xb[gof[j] + ro];
                av[j] = f2bf(v);
            }
        } else {
            float v = 0.f;
            if (rk && ((gokm >> 8) & 1)) v = xb[gof[8] + ro];
            av[0] = f2bf(v);
        }
        F[f] = make_uint4((u32)av[0] | ((u32)av[1] << 16),
                          (u32)av[2] | ((u32)av[3] << 16),
                          (u32)av[4] | ((u32)av[5] << 16),
                          (u32)av[6] | ((u32)av[7] << 16));
    }

    f32x16 acc[4];
#pragma unroll
    for (int r = 0; r < 4; ++r)
#pragma unroll
        for (int e = 0; e < 16; ++e) acc[r][e] = 0.f;
#pragma unroll
    for (int ss = 0; ss < 3; ++ss)
#pragma unroll
        for (int r = 0; r < 4; ++r)
            acc[r] = __builtin_amdgcn_mfma_f32_32x32x16_bf16(
                __builtin_bit_cast(bf16x8, F[r + ss]),
                __builtin_bit_cast(bf16x8, Bs[ss]), acc[r], 0, 0, 0);

    float* Ew = E[wv];
    for (int r = 0; r < 4; ++r) {
        if (wv == 3 && r == 3) continue;
#pragma unroll
        for (int gq = 0; gq < 4; ++gq)
#pragma unroll
            for (int r4 = 0; r4 < 4; ++r4)
                Ew[m * 33 + 4 * hl + 8 * gq + r4] = acc[r][gq * 4 + r4];

        const int h2 = rbase + r;
        char* pl = (char*)outp + ((size_t)b * 900 + h1 * S + w1i) * PLANE
                   + (size_t)(h2 + 1) * 1024;
        const int t = lane >> 1, h8 = lane & 1;
        if (t < 30) {
            u32 wo[4];
#pragma unroll
            for (int p = 0; p < 4; ++p) {
                const int c0 = 8 * h8 + 2 * p, c1 = c0 + 1;
                float v0 = 0.f, v1 = 0.f;
                if (c0 < 10)
                    v0 = fmaxf(Ew[c0 * 33 + t] + Ew[(10 + c0) * 33 + t + 1]
                             + Ew[(20 + c0) * 33 + t + 2] + bias[c0], 0.f);
                if (c1 < 10)
                    v1 = fmaxf(Ew[c1 * 33 + t] + Ew[(10 + c1) * 33 + t + 1]
                             + Ew[(20 + c1) * 33 + t + 2] + bias[c1], 0.f);
                wo[p] = (u32)f2bf(v0) | ((u32)f2bf(v1) << 16);
            }
            *(uint4*)(pl + (t + 1) * 32 + h8 * 16) =
                make_uint4(wo[0], wo[1], wo[2], wo[3]);
        }
    }
}

// ---------------------------------------------------------------------------
// Layers 1/2: 5 waves x 3 rows (320 threads). rbase = half*15 + wv*3;
// rows rbase..rbase+4 needed (max 31, never OOB, no clamp, no junk rows).
// Per tap: 5 A-loads (rotate depth-1 prefetch) + 3 B ds_reads + 9 MFMAs.
// acc = 3 x f32x16 = 48 AGPR; arch ~75 -> total ~123 <= 128 -> 4 w/SIMD.
// LDS: BT (27648) unioned with epilogue E (21120) behind one barrier.
template<int LAYER, bool ACCUM>
__global__ __launch_bounds__(320, 4) void conv_k(
    const void* __restrict__ inp, const u32* __restrict__ ftab,
    const float* __restrict__ bias, void* __restrict__ outp)
{
    __shared__ char SH[27648];            // BT during taps; E in epilogue
    uint4* BT = (uint4*)SH;               // [k12(9)][k3(3)][lane(64)]

    const int tid = threadIdx.x;
    // ---- stage B table to LDS (27.6 KB, once per block) ----
    {
        const uint4* g = (const uint4*)ftab;
#pragma unroll
        for (int j = 0; j < 6; ++j) {
            const int idx = j * 320 + tid;
            if (idx < 1728) BT[idx] = g[idx];
        }
    }
    __syncthreads();

    const int wgid = blockIdx.x + S * blockIdx.y + 900 * blockIdx.z;
    const int id2  = (wgid & 7) * 450 + (wgid >> 3);
    const int half = id2 & 1;
    int sp = id2 >> 1;
    const int w1i = sp % S; sp /= S;
    const int h1  = sp % S;
    const int b   = sp / S;

    const int lane = tid & 63, wv = tid >> 6;       // wv in 0..4
    const int m = lane & 31, hl = lane >> 5;
    const int rbase = half * 15 + wv * 3;           // rows rbase..rbase+4

    int kl[9], nk = 0;
#pragma unroll
    for (int k12 = 0; k12 < 9; ++k12) {
        const int g1 = h1 + k12 / 3 - 1, g2 = w1i + k12 % 3 - 1;
        if (g1 >= 0 && g1 < S && g2 >= 0 && g2 < S)
            kl[nk++] = (g1 * S + g2) | (k12 << 10);
    }

    f32x16 acc[3];
#pragma unroll
    for (int r = 0; r < 3; ++r)
#pragma unroll
        for (int e = 0; e < 16; ++e) acc[r][e] = 0.f;

    const char* Pb = (const char*)inp + (size_t)b * 900 * PLANE
                     + (size_t)rbase * 1024 + m * 32 + hl * 16;

    auto loadA = [&](uint4* Fd, int g) {
        const char* P = Pb + (size_t)g * PLANE;
        Fd[0] = *(const uint4*)(P);
        Fd[1] = *(const uint4*)(P + 1024);
        Fd[2] = *(const uint4*)(P + 2048);
        Fd[3] = *(const uint4*)(P + 3072);
        Fd[4] = *(const uint4*)(P + 4096);
    };
    auto mfma9 = [&](const uint4* Fs, const uint4* Bs) {
#pragma unroll
        for (int ss = 0; ss < 3; ++ss)
#pragma unroll
            for (int r = 0; r < 3; ++r)
                acc[r] = __builtin_amdgcn_mfma_f32_32x32x16_bf16(
                    __builtin_bit_cast(bf16x8, Fs[r + ss]),
                    __builtin_bit_cast(bf16x8, Bs[ss]), acc[r], 0, 0, 0);
    };

    uint4 F[5];
    loadA(F, kl[0] & 1023);

    for (int ki = 0; ki + 1 < nk; ++ki) {
        uint4 FN[5];
        loadA(FN, kl[ki + 1] & 1023);
        uint4 B0[3];
        {
            const int kk = kl[ki] >> 10;
#pragma unroll
            for (int f = 0; f < 3; ++f) B0[f] = BT[(kk * 3 + f) * 64 + lane];
        }
        mfma9(F, B0);
#pragma unroll
        for (int f = 0; f < 5; ++f) F[f] = FN[f];
    }
    {
        uint4 B0[3];
        const int kk = kl[nk - 1] >> 10;
#pragma unroll
        for (int f = 0; f < 3; ++f) B0[f] = BT[(kk * 3 + f) * 64 + lane];
        mfma9(F, B0);
    }

    // ---- epilogue: E overlays BT; all waves must be done with BT ----
    __syncthreads();
    float* Ew = (float*)SH + wv * 1056;
    for (int r = 0; r < 3; ++r) {
#pragma unroll
        for (int gq = 0; gq < 4; ++gq)
#pragma unroll
            for (int r4 = 0; r4 < 4; ++r4)
                Ew[m * 33 + 4 * hl + 8 * gq + r4] = acc[r][gq * 4 + r4];

        const int h2 = rbase + r;
        if (LAYER <= 1) {
            char* pl = (char*)outp + ((size_t)b * 900 + h1 * S + w1i) * PLANE
                       + (size_t)(h2 + 1) * 1024;
            const int t = lane >> 1, h8 = lane & 1;
            if (t < 30) {
                u32 wo[4];
#pragma unroll
                for (int p = 0; p < 4; ++p) {
                    const int c0 = 8 * h8 + 2 * p, c1 = c0 + 1;
                    float v0 = 0.f, v1 = 0.f;
                    if (c0 < 10)
                        v0 = fmaxf(Ew[c0 * 33 + t] + Ew[(10 + c0) * 33 + t + 1]
                                 + Ew[(20 + c0) * 33 + t + 2] + bias[c0], 0.f);
                    if (c1 < 10)
                        v1 = fmaxf(Ew[c1 * 33 + t] + Ew[(10 + c1) * 33 + t + 1]
                                 + Ew[(20 + c1) * 33 + t + 2] + bias[c1], 0.f);
                    wo[p] = (u32)f2bf(v0) | ((u32)f2bf(v1) << 16);
                }
                *(uint4*)(pl + (t + 1) * 32 + h8 * 16) =
                    make_uint4(wo[0], wo[1], wo[2], wo[3]);
            }
        } else {
            if (lane < 30) {
                const int t = lane;
                float v = Ew[t] + Ew[330 + t + 1] + Ew[660 + t + 2] + bias[0];
                v = fmaxf(v, 0.f);
                float* o = (float*)outp + (size_t)b * S4
                           + (size_t)(h1 * S + w1i) * 900 + h2 * 30 + t;
                if (ACCUM) *o += v; else *o = v;
            }
        }
    }
}

// ---------------------------------------------------------------------------
extern "C" void kernel_launch(void* const* d_in, const int* in_sizes, int n_in,
                              void* d_out, int out_size, void* d_ws, size_t ws_size,
                              hipStream_t stream)
{
    const float* x   = (const float*)d_in[0];
    const float* w1p = (const float*)d_in[1];
    const float* b1p = (const float*)d_in[2];
    const float* w2p = (const float*)d_in[3];
    const float* b2p = (const float*)d_in[4];
    const float* w3p = (const float*)d_in[5];
    const float* b3p = (const float*)d_in[6];
    float* out = (float*)d_out;

    // ws: fragtab (6*27*64 + 2*3*64) uint4 = 172032 B | y1 59 MB | y2 59 MB
    u32* ft = (u32*)d_ws;
    const uint4* ftL0 = (const uint4*)d_ws + 6 * 27 * 64;
    u16* y1 = (u16*)((char*)d_ws + 172032);
    u16* y2 = (u16*)((char*)y1 + YBYTES);

    fragprep_k<<<42, 256, 0, stream>>>(ft, w1p, w2p, w3p);
    zerok<<<1800, 128, 0, stream>>>(y1, y2);

    dim3 grid(S, S, 4);
    for (int br = 0; br < 2; ++br) {
        const u32* f2 = ft + (size_t)(2 + br) * 27 * 64 * 4;
        const u32* f3 = ft + (size_t)(4 + br) * 27 * 64 * 4;
        conv0_k<<<grid, 256, 0, stream>>>(x, ftL0 + br * 192, b1p, (void*)y1);
        conv_k<1, false><<<grid, 320, 0, stream>>>(y1, f2, b2p, (void*)y2);
        if (br == 0)
            conv_k<2, false><<<grid, 320, 0, stream>>>(y2, f3, b3p, (void*)out);
        else
            conv_k<2, true><<<grid, 320, 0, stream>>>(y2, f3, b3p, (void*)out);
    }
}